// Round 1
// 3474.642 us; speedup vs baseline: 3.1380x; 3.1380x over previous
//
#include <hip/hip_runtime.h>
#include <cmath>

#define TT 512
#define BB 32
#define HH 100
#define EE 50
#define NL 5
#define VV 10000
#define CCH 8          // chunk = 8 timesteps per cross-layer handoff
#define PROGSTR 16     // ints per flag slot (64B line each, no false sharing)

__device__ __forceinline__ float sigmf(float x) { return 1.f / (1.f + __expf(-x)); }

__device__ __forceinline__ void waitge(int* p, int target) {
    int spins = 0;
    while (__hip_atomic_load(p, __ATOMIC_ACQUIRE, __HIP_MEMORY_SCOPE_AGENT) < target) {
        if (++spins > 30000000) break;
    }
}

// Batch-split LSTM recurrence. Block (l,b): layer l, batch row b, ALL 400 gate
// columns. Weights live in registers: thread (j = tid>>1, kh = tid&1) holds
// W[4 gates][100 k] for its k-half of the combined input v = [x(100); h(100)]
// (layer 0: x = 50 emb + 50 zero-pad, weights padded with zeros -> one code path).
// h recurrence never leaves the block (LDS double-buffer vbuf). Cross-layer
// handoff via global ring, chunked every CCH steps: 1 flag poll / 8 steps.
__global__ __launch_bounds__(256, 1) void lstm_rec2(
    const int* __restrict__ toks, const float* __restrict__ emb,
    const float* __restrict__ Wx0, const float* __restrict__ Wh0, const float* __restrict__ b0,
    const float* __restrict__ WxU, const float* __restrict__ WhU, const float* __restrict__ bU,
    float* __restrict__ ring, float* __restrict__ h4, int* __restrict__ prog, int RS)
{
    const int l = blockIdx.x >> 5;
    const int b = blockIdx.x & 31;
    const int tid = threadIdx.x;
    const int j = tid >> 1;          // hidden unit owned (0..99 for active lanes)
    const int kh = tid & 1;          // k-half: 0 -> v[0..99] (x), 1 -> v[100..199] (h)
    const bool act = (tid < 2 * HH);
    const int jc = (j < HH) ? j : HH - 1;   // clamped addr for idle lanes

    __shared__ __align__(16) float vbuf[2][224];  // [parity][0..99 x | 100..199 h]

    const float* WxL = (l == 0) ? Wx0 : WxU + (size_t)(l - 1) * (HH * 400);
    const float* WhL = (l == 0) ? Wh0 : WhU + (size_t)(l - 1) * (HH * 400);
    const float* bL  = (l == 0) ? b0  : bU  + (size_t)(l - 1) * 400;

    // ---- one-time: weights into registers (static indices only) ----
    float W[4][HH];
    float bias[4];
    #pragma unroll
    for (int g = 0; g < 4; ++g) {
        const int c = g * HH + jc;
        bias[g] = bL[c];
        if (kh == 0) {
            #pragma unroll
            for (int kk = 0; kk < HH; ++kk) {
                float v = 0.f;
                if (l != 0 || kk < EE) v = WxL[kk * 400 + c];  // zero-pad l0 kk>=50
                W[g][kk] = v;
            }
        } else {
            #pragma unroll
            for (int kk = 0; kk < HH; ++kk) W[g][kk] = WhL[kk * 400 + c];
        }
    }

    const int ringstr = RS * CCH * HH;   // floats per (l,b) ring
    const int rsm = RS - 1;
    int* progSelf = prog + (l * 32 + b) * PROGSTR;
    int* progDown = prog + ((l - 1) * 32 + b) * PROGSTR;
    int* progUp   = prog + ((l + 1) * 32 + b) * PROGSTR;
    const float* ringDown = ring + (size_t)((l - 1) * 32 + b) * ringstr;
    float*       ringSelf = ring + (size_t)(l * 32 + b) * ringstr;
    float*       h4b      = h4 + (size_t)b * HH;

    // ---- prologue: stage v for t=0 (h = 0, x = x[0]) ----
    if (tid < HH) vbuf[0][HH + tid] = 0.f;
    if (l > 0) {
        if (tid == 0) waitge(progDown, 1);   // chunk 0 from layer below
        __syncthreads();
        if (tid < HH) vbuf[0][tid] = ringDown[tid];  // slot0, tc0
    } else {
        if (tid < HH) {
            float xv = 0.f;
            if (tid < EE) { int tok = toks[b * TT]; xv = emb[(size_t)tok * EE + tid]; }
            vbuf[0][tid] = xv;
        }
    }
    __syncthreads();

    float cstate = 0.f;

    for (int t = 0; t < TT; ++t) {
        const int p = t & 1;
        // chunk-boundary waits (tid0 only; amortized over 8 steps)
        if (tid == 0) {
            if ((t & 7) == 0 && l < NL - 1) {
                int e = t >> 3;
                if (e >= RS) waitge(progUp, e - RS + 1);   // back-pressure: slot free
            }
            if (((t + 1) & 7) == 0 && (t + 1) < TT && l > 0)
                waitge(progDown, ((t + 1) >> 3) + 1);      // next x-chunk available
        }
        __syncthreads();   // orders prev-step vnext writes + flag waits

        // prefetch x[t+1] (odd active lanes); latency hides under FMA loop
        const int tn = t + 1;
        float xp = 0.f;
        if (act && kh == 1 && tn < TT) {
            if (l == 0) {
                if (j < EE) { int tok = toks[b * TT + tn]; xp = emb[(size_t)tok * EE + j]; }
            } else {
                xp = ringDown[(size_t)((((tn >> 3) & rsm) * CCH) + (tn & 7)) * HH + j];
            }
        }

        // gates: acc[g] = sum over this lane's k-half of W[g][k] * v[k]
        float acc[4] = {0.f, 0.f, 0.f, 0.f};
        const float* vb = &vbuf[p][kh * HH];
        #pragma unroll
        for (int kk = 0; kk < 25; ++kk) {
            const float4 vv = *reinterpret_cast<const float4*>(vb + 4 * kk);
            #pragma unroll
            for (int g = 0; g < 4; ++g) {
                acc[g] = fmaf(vv.x, W[g][4 * kk + 0], acc[g]);
                acc[g] = fmaf(vv.y, W[g][4 * kk + 1], acc[g]);
                acc[g] = fmaf(vv.z, W[g][4 * kk + 2], acc[g]);
                acc[g] = fmaf(vv.w, W[g][4 * kk + 3], acc[g]);
            }
        }
        // pair-reduce the two k-halves (lanes 2j <-> 2j+1)
        #pragma unroll
        for (int g = 0; g < 4; ++g) acc[g] += __shfl_xor(acc[g], 1);

        if (act) {
            if (kh == 0) {
                // full LSTM cell for hidden unit j; gate order i,f,o,ct
                float gi = acc[0] + bias[0], gf = acc[1] + bias[1];
                float go = acc[2] + bias[2], gc = acc[3] + bias[3];
                float cn = sigmf(gf) * cstate + sigmf(gi) * tanhf(gc);
                cstate = cn;
                float hn = sigmf(go) * tanhf(cn);
                vbuf[p ^ 1][HH + j] = hn;                       // local recurrence
                if (l == NL - 1) h4b[(size_t)t * (BB * HH) + j] = hn;
                else ringSelf[(size_t)((((t >> 3) & rsm) * CCH) + (t & 7)) * HH + j] = hn;
            } else {
                vbuf[p ^ 1][j] = xp;   // x for next step (0-pad for l0 j>=50, t=511)
            }
        }

        // publish finished chunk (all layers: l+1 consumes x, l-1 uses as BP)
        if ((t & 7) == 7) {
            __syncthreads();
            __threadfence();
            if (tid == 0)
                __hip_atomic_store(progSelf, (t >> 3) + 1, __ATOMIC_RELEASE,
                                   __HIP_MEMORY_SCOPE_AGENT);
        }
    }
}

// out[b*512+t][v] = h4[t][b][:] . fc_w[:,v] + fc_b[v]
// 128x128 tile, 256 threads, 8x8 per thread, float4 LDS reads (4 LDS / 64 FMA).
__global__ __launch_bounds__(256) void fc2(
    const float* __restrict__ h4, const float* __restrict__ fcw,
    const float* __restrict__ fcb, float* __restrict__ out)
{
    const int v0 = blockIdx.x * 128;
    const int R0 = blockIdx.y * 128;   // 128 rows share one b (128 | 512)
    const int tid = threadIdx.x;
    const int tv = tid & 15, tr = tid >> 4;
    __shared__ __align__(16) float As[HH][132];   // [k][row], stride 132 (odd 16B)
    __shared__ __align__(16) float Bs[HH][132];   // [k][col]
    const int b = R0 >> 9;
    const int t0 = R0 & 511;

    for (int idx = tid; idx < 128 * HH; idx += 256) {
        int r = idx / HH, k = idx - r * HH;
        As[k][r] = h4[(size_t)(t0 + r) * (BB * HH) + b * HH + k];
    }
    for (int idx = tid; idx < HH * 128; idx += 256) {
        int k = idx >> 7, vl = idx & 127;
        int v = v0 + vl;
        Bs[k][vl] = (v < VV) ? fcw[(size_t)k * VV + v] : 0.f;
    }
    __syncthreads();

    float acc[8][8];
    #pragma unroll
    for (int i = 0; i < 8; ++i)
        #pragma unroll
        for (int q = 0; q < 8; ++q) acc[i][q] = 0.f;

    for (int k = 0; k < HH; ++k) {
        const float4 aL = *reinterpret_cast<const float4*>(&As[k][4 * tr]);
        const float4 aH = *reinterpret_cast<const float4*>(&As[k][64 + 4 * tr]);
        const float4 bL = *reinterpret_cast<const float4*>(&Bs[k][4 * tv]);
        const float4 bH = *reinterpret_cast<const float4*>(&Bs[k][64 + 4 * tv]);
        const float a[8] = {aL.x, aL.y, aL.z, aL.w, aH.x, aH.y, aH.z, aH.w};
        const float bb[8] = {bL.x, bL.y, bL.z, bL.w, bH.x, bH.y, bH.z, bH.w};
        #pragma unroll
        for (int i = 0; i < 8; ++i)
            #pragma unroll
            for (int q = 0; q < 8; ++q)
                acc[i][q] = fmaf(a[i], bb[q], acc[i][q]);
    }

    #pragma unroll
    for (int i = 0; i < 8; ++i) {
        const int r = R0 + 64 * (i >> 2) + 4 * tr + (i & 3);
        float* orow = out + (size_t)r * VV;
        #pragma unroll
        for (int ch = 0; ch < 2; ++ch) {
            const int v = v0 + 64 * ch + 4 * tv;
            if (v + 3 < VV) {
                float4 o;
                o.x = acc[i][4 * ch + 0] + fcb[v + 0];
                o.y = acc[i][4 * ch + 1] + fcb[v + 1];
                o.z = acc[i][4 * ch + 2] + fcb[v + 2];
                o.w = acc[i][4 * ch + 3] + fcb[v + 3];
                *reinterpret_cast<float4*>(orow + v) = o;
            } else {
                #pragma unroll
                for (int q = 0; q < 4; ++q)
                    if (v + q < VV) orow[v + q] = acc[i][4 * ch + q] + fcb[v + q];
            }
        }
    }
}

extern "C" void kernel_launch(void* const* d_in, const int* in_sizes, int n_in,
                              void* d_out, int out_size, void* d_ws, size_t ws_size,
                              hipStream_t stream)
{
    const int*   toks = (const int*)d_in[0];
    const float* emb  = (const float*)d_in[1];
    const float* Wx0  = (const float*)d_in[2];
    const float* Wh0  = (const float*)d_in[3];
    const float* b0   = (const float*)d_in[4];
    const float* WxU  = (const float*)d_in[5];
    const float* WhU  = (const float*)d_in[6];
    const float* bU   = (const float*)d_in[7];
    const float* fcw  = (const float*)d_in[8];
    const float* fcb  = (const float*)d_in[9];
    float* out = (float*)d_out;

    // ws: [prog 5*32*PROGSTR ints | pad to 16K][ring 4*32*RS*8*100 f32][h4 512*3200 f32]
    // RS=4 if workspace allows (decouples back-pressure), else RS=2 (fits the
    // exact footprint of the previous kernel: 16384 + 819200 + 6553600 bytes).
    char* ws = (char*)d_ws;
    int* prog = (int*)ws;
    const size_t h4_bytes = (size_t)TT * BB * HH * 4;
    const size_t ring4 = (size_t)4 * 32 * 4 * CCH * HH * 4;
    int RS = (ws_size >= 16384 + ring4 + h4_bytes) ? 4 : 2;
    float* ring = (float*)(ws + 16384);
    float* h4   = (float*)(ws + 16384 + (size_t)4 * 32 * RS * CCH * HH * 4);

    hipMemsetAsync(ws, 0, 16384, stream);
    lstm_rec2<<<NL * 32, 256, 0, stream>>>(toks, emb, Wx0, Wh0, b0,
                                           WxU, WhU, bU, ring, h4, prog, RS);
    fc2<<<dim3((VV + 127) / 128, (BB * TT) / 128), 256, 0, stream>>>(h4, fcw, fcb, out);
}

// Round 2
// 3465.633 us; speedup vs baseline: 3.1462x; 1.0026x over previous
//
#include <hip/hip_runtime.h>
#include <cmath>

#define TT 512
#define BB 32
#define HH 100
#define EE 50
#define NL 5
#define VV 10000
#define CCH 8          // chunk = 8 timesteps per cross-layer handoff
#define PROGSTR 16     // ints per flag slot (64B line each, no false sharing)

__device__ __forceinline__ float sigmf(float x) { return 1.f / (1.f + __expf(-x)); }

__device__ __forceinline__ void waitge(int* p, int target) {
    int spins = 0;
    while (__hip_atomic_load(p, __ATOMIC_ACQUIRE, __HIP_MEMORY_SCOPE_AGENT) < target) {
        if (++spins > 30000000) break;
    }
}

// Batch-split LSTM recurrence, 512 threads/block so per-thread weight state
// fits in arch VGPRs (<=256; the 256-thread version needed 400 -> spilled).
// Block (l,b). Thread (j = tid>>2, s = tid&3): s&1 = k-half of the combined
// input v = [x(100); h(100)] (both halves 100-aligned -> aligned float4 LDS
// reads), s>>1 = gate pair. W[2][100] = 200 VGPRs. Gate k-halves reduced with
// shfl_xor(1); gates redistributed so lanes s=0..3 evaluate sigma/sigma/sigma/
// tanh in parallel, cell assembled in lane s==0 via shfl_xor(1/2/3).
// h recurrence stays in LDS (vbuf double buffer); cross-layer handoff via
// global ring, chunked every CCH steps (1 flag poll / 8 steps).
__global__ __launch_bounds__(512, 2) void lstm_rec3(
    const int* __restrict__ toks, const float* __restrict__ emb,
    const float* __restrict__ Wx0, const float* __restrict__ Wh0, const float* __restrict__ b0,
    const float* __restrict__ WxU, const float* __restrict__ WhU, const float* __restrict__ bU,
    float* __restrict__ ring, float* __restrict__ h4, int* __restrict__ prog, int RS)
{
    const int l = blockIdx.x >> 5;
    const int b = blockIdx.x & 31;
    const int tid = threadIdx.x;
    const int j = tid >> 2;          // hidden unit owned (0..127; active j<100)
    const int s = tid & 3;           // sub-lane: (s&1)=k-half, (s>>1)=gate pair
    const int khalf = s & 1;
    const int gp = s >> 1;
    const bool act = (j < HH);
    const int jc = act ? j : HH - 1; // clamped addr for idle lanes

    __shared__ __align__(16) float vbuf[2][208];  // [parity][0..99 x | 100..199 h]

    const float* WxL = (l == 0) ? Wx0 : WxU + (size_t)(l - 1) * (HH * 400);
    const float* WhL = (l == 0) ? Wh0 : WhU + (size_t)(l - 1) * (HH * 400);
    const float* bL  = (l == 0) ? b0  : bU  + (size_t)(l - 1) * 400;

    // ---- one-time: weights into registers (static indices only) ----
    float W[2][HH];
    {
        const float* Wsrc = khalf ? WhL : WxL;
        #pragma unroll
        for (int gg = 0; gg < 2; ++gg) {
            const int c = (2 * gp + gg) * HH + jc;
            #pragma unroll
            for (int kk = 0; kk < HH; ++kk) {
                float w = 0.f;
                if (khalf == 1 || l != 0 || kk < EE) w = Wsrc[kk * 400 + c];
                W[gg][kk] = w;   // zero-pad layer0 x-rows kk>=EE
            }
        }
    }
    const float biasv = bL[s * HH + jc];   // lane s evaluates gate s

    const int ringstr = RS * CCH * HH;   // floats per (l,b) ring
    const int rsm = RS - 1;
    int* progSelf = prog + (l * 32 + b) * PROGSTR;
    int* progDown = prog + ((l - 1) * 32 + b) * PROGSTR;
    int* progUp   = prog + ((l + 1) * 32 + b) * PROGSTR;
    const float* ringDown = ring + (size_t)((l - 1) * 32 + b) * ringstr;
    float*       ringSelf = ring + (size_t)(l * 32 + b) * ringstr;
    float*       h4b      = h4 + (size_t)b * HH;
    const int*   tokb     = toks + b * TT;

    // ---- prologue: stage v for t=0 (h = 0, x = x[0]) ----
    if (tid < HH) vbuf[0][HH + tid] = 0.f;
    if (l > 0) {
        if (tid == 0) waitge(progDown, 1);   // chunk 0 from layer below
        __syncthreads();
        if (tid < HH) vbuf[0][tid] = ringDown[tid];  // slot0, step0
    } else {
        if (tid < HH) {
            float xv = 0.f;
            if (tid < EE) { int tok = tokb[0]; xv = emb[(size_t)tok * EE + tid]; }
            vbuf[0][tid] = xv;
        }
    }
    __syncthreads();

    float cstate = 0.f;

    for (int t = 0; t < TT; ++t) {
        const int p = t & 1;
        // chunk-boundary waits (tid0 only; amortized over 8 steps)
        if (tid == 0) {
            if ((t & 7) == 0 && l < NL - 1) {
                int e = t >> 3;
                if (e >= RS) waitge(progUp, e - RS + 1);   // back-pressure
            }
            if (((t + 1) & 7) == 0 && (t + 1) < TT && l > 0)
                waitge(progDown, ((t + 1) >> 3) + 1);      // next x-chunk ready
        }
        __syncthreads();   // orders prev-step vbuf writes + flag waits

        // prefetch x[t+1] (s==1 lanes); latency hides under FMA loop
        const int tn = t + 1;
        float xp = 0.f;
        if (act && s == 1 && tn < TT) {
            if (l == 0) {
                if (j < EE) { int tok = tokb[tn]; xp = emb[(size_t)tok * EE + j]; }
            } else {
                xp = ringDown[(size_t)((((tn >> 3) & rsm) * CCH) + (tn & 7)) * HH + j];
            }
        }

        // partial gates: this lane's 2 gates over its k-half (100 k, float4)
        float acc0 = 0.f, acc1 = 0.f;
        const float* vb = &vbuf[p][khalf * HH];
        #pragma unroll
        for (int kk = 0; kk < 25; ++kk) {
            const float4 vv = *reinterpret_cast<const float4*>(vb + 4 * kk);
            acc0 = fmaf(vv.x, W[0][4 * kk + 0], acc0);
            acc0 = fmaf(vv.y, W[0][4 * kk + 1], acc0);
            acc0 = fmaf(vv.z, W[0][4 * kk + 2], acc0);
            acc0 = fmaf(vv.w, W[0][4 * kk + 3], acc0);
            acc1 = fmaf(vv.x, W[1][4 * kk + 0], acc1);
            acc1 = fmaf(vv.y, W[1][4 * kk + 1], acc1);
            acc1 = fmaf(vv.z, W[1][4 * kk + 2], acc1);
            acc1 = fmaf(vv.w, W[1][4 * kk + 3], acc1);
        }
        // reduce the two k-halves (lanes s <-> s^1 hold the same gate pair)
        acc0 += __shfl_xor(acc0, 1);
        acc1 += __shfl_xor(acc1, 1);

        // redistribute: lane s evaluates gate s (order i,f,o,ct)
        float g = ((s & 1) ? acc1 : acc0) + biasv;
        float es = (s == 3) ? tanhf(g) : sigmf(g);
        float f1 = __shfl_xor(es, 1);   // at s0: sigma(f)
        float f2 = __shfl_xor(es, 2);   // at s0: sigma(o)
        float f3 = __shfl_xor(es, 3);   // at s0: tanh(ct)

        if (act) {
            if (s == 0) {
                float cn = f1 * cstate + es * f3;
                cstate = cn;
                float hn = f2 * tanhf(cn);
                vbuf[p ^ 1][HH + j] = hn;                     // local recurrence
                if (l == NL - 1) h4b[(size_t)t * (BB * HH) + j] = hn;
                else ringSelf[(size_t)((((t >> 3) & rsm) * CCH) + (t & 7)) * HH + j] = hn;
            } else if (s == 1) {
                vbuf[p ^ 1][j] = xp;   // x for next step
            }
        }

        // publish finished chunk (l+1 consumes x; l-1 uses as back-pressure)
        if ((t & 7) == 7) {
            __syncthreads();
            __threadfence();
            if (tid == 0)
                __hip_atomic_store(progSelf, (t >> 3) + 1, __ATOMIC_RELEASE,
                                   __HIP_MEMORY_SCOPE_AGENT);
        }
    }
}

// out[b*512+t][v] = h4[t][b][:] . fc_w[:,v] + fc_b[v]
// 64x128 tile, 80KB LDS -> 2 blocks/CU (phase overlap). 256 threads, 4x8 per
// thread: 3 ds_read_b128 per 32 FMA, conflict-free reads (pads 68 / 132).
__global__ __launch_bounds__(256) void fc3(
    const float* __restrict__ h4, const float* __restrict__ fcw,
    const float* __restrict__ fcb, float* __restrict__ out)
{
    const int v0 = blockIdx.x * 128;
    const int R0 = blockIdx.y * 64;    // 64 consecutive rows share one b
    const int tid = threadIdx.x;
    const int tv = tid & 15, tr = tid >> 4;
    __shared__ __align__(16) float As[HH][68];    // [k][row] 27.2KB
    __shared__ __align__(16) float Bs[HH][132];   // [k][col] 52.8KB
    const int b = R0 >> 9;
    const int t0 = R0 & 511;

    for (int idx = tid; idx < 64 * HH; idx += 256) {
        int rr = idx / HH, kk = idx - rr * HH;     // global side coalesced
        As[kk][rr] = h4[(size_t)(t0 + rr) * (BB * HH) + b * HH + kk];
    }
    for (int i4 = tid; i4 < HH * 32; i4 += 256) {  // Bs staged as float4
        int k = i4 >> 5, m = i4 & 31;
        int v = v0 + 4 * m;
        float4 w;
        if (v + 3 < VV) {
            w = *reinterpret_cast<const float4*>(fcw + (size_t)k * VV + v);
        } else {
            w.x = (v + 0 < VV) ? fcw[(size_t)k * VV + v + 0] : 0.f;
            w.y = (v + 1 < VV) ? fcw[(size_t)k * VV + v + 1] : 0.f;
            w.z = (v + 2 < VV) ? fcw[(size_t)k * VV + v + 2] : 0.f;
            w.w = (v + 3 < VV) ? fcw[(size_t)k * VV + v + 3] : 0.f;
        }
        *reinterpret_cast<float4*>(&Bs[k][4 * m]) = w;
    }
    __syncthreads();

    float acc[4][8];
    #pragma unroll
    for (int i = 0; i < 4; ++i)
        #pragma unroll
        for (int q = 0; q < 8; ++q) acc[i][q] = 0.f;

    for (int k = 0; k < HH; ++k) {
        const float4 a4 = *reinterpret_cast<const float4*>(&As[k][4 * tr]);
        const float4 bL = *reinterpret_cast<const float4*>(&Bs[k][4 * tv]);
        const float4 bH = *reinterpret_cast<const float4*>(&Bs[k][64 + 4 * tv]);
        const float a[4] = {a4.x, a4.y, a4.z, a4.w};
        const float bb[8] = {bL.x, bL.y, bL.z, bL.w, bH.x, bH.y, bH.z, bH.w};
        #pragma unroll
        for (int i = 0; i < 4; ++i)
            #pragma unroll
            for (int q = 0; q < 8; ++q)
                acc[i][q] = fmaf(a[i], bb[q], acc[i][q]);
    }

    #pragma unroll
    for (int i = 0; i < 4; ++i) {
        const int r = R0 + 4 * tr + i;
        float* orow = out + (size_t)r * VV;
        #pragma unroll
        for (int ch = 0; ch < 2; ++ch) {
            const int v = v0 + 64 * ch + 4 * tv;
            if (v + 3 < VV) {
                float4 o;
                o.x = acc[i][4 * ch + 0] + fcb[v + 0];
                o.y = acc[i][4 * ch + 1] + fcb[v + 1];
                o.z = acc[i][4 * ch + 2] + fcb[v + 2];
                o.w = acc[i][4 * ch + 3] + fcb[v + 3];
                *reinterpret_cast<float4*>(orow + v) = o;
            } else {
                #pragma unroll
                for (int q = 0; q < 4; ++q)
                    if (v + q < VV) orow[v + q] = acc[i][4 * ch + q] + fcb[v + q];
            }
        }
    }
}

extern "C" void kernel_launch(void* const* d_in, const int* in_sizes, int n_in,
                              void* d_out, int out_size, void* d_ws, size_t ws_size,
                              hipStream_t stream)
{
    const int*   toks = (const int*)d_in[0];
    const float* emb  = (const float*)d_in[1];
    const float* Wx0  = (const float*)d_in[2];
    const float* Wh0  = (const float*)d_in[3];
    const float* b0   = (const float*)d_in[4];
    const float* WxU  = (const float*)d_in[5];
    const float* WhU  = (const float*)d_in[6];
    const float* bU   = (const float*)d_in[7];
    const float* fcw  = (const float*)d_in[8];
    const float* fcb  = (const float*)d_in[9];
    float* out = (float*)d_out;

    // ws: [prog 5*32*PROGSTR ints | pad to 16K][ring 4*32*RS*CCH*100 f32][h4]
    char* ws = (char*)d_ws;
    int* prog = (int*)ws;
    const size_t h4_bytes = (size_t)TT * BB * HH * 4;
    const size_t ring4 = (size_t)4 * 32 * 4 * CCH * HH * 4;
    int RS = (ws_size >= 16384 + ring4 + h4_bytes) ? 4 : 2;
    float* ring = (float*)(ws + 16384);
    float* h4   = (float*)(ws + 16384 + (size_t)4 * 32 * RS * CCH * HH * 4);

    hipMemsetAsync(ws, 0, 16384, stream);
    lstm_rec3<<<NL * 32, 512, 0, stream>>>(toks, emb, Wx0, Wh0, b0,
                                           WxU, WhU, bU, ring, h4, prog, RS);
    fc3<<<dim3((VV + 127) / 128, (BB * TT) / 64), 256, 0, stream>>>(h4, fcw, fcb, out);
}